// Round 1
// baseline (183.392 us; speedup 1.0000x reference)
//
#include <hip/hip_runtime.h>
#include <stdint.h>

// Problem constants
#define T_SEQ   2048
#define DMODEL  2048
#define NH      16
#define HD      128
#define QKVN    3072
#define KCOL    2048   // col offset of k in qkv
#define VCOL    2560   // col offset of v in qkv

typedef __bf16 bf16x8 __attribute__((ext_vector_type(8)));
typedef float  f32x4  __attribute__((ext_vector_type(4)));
typedef unsigned short u16x8 __attribute__((ext_vector_type(8)));

__device__ __forceinline__ uint16_t f2bf(float f) {
    uint32_t u = __builtin_bit_cast(uint32_t, f);
    u += 0x7fffu + ((u >> 16) & 1u);
    return (uint16_t)(u >> 16);
}
__device__ __forceinline__ u16x8 ld8(const uint16_t* p) {
    return *reinterpret_cast<const u16x8*>(p);
}
__device__ __forceinline__ void st8(uint16_t* p, u16x8 v) {
    *reinterpret_cast<u16x8*>(p) = v;
}
__device__ __forceinline__ bf16x8 as_bf(u16x8 v) { return __builtin_bit_cast(bf16x8, v); }

// ---------------------------------------------------------------- cast x -> bf16
__global__ __launch_bounds__(256) void k_cast(const float* __restrict__ in,
                                              uint16_t* __restrict__ out, int n8) {
    int i = blockIdx.x * 256 + threadIdx.x;
    if (i >= n8) return;
    const f32x4* p = reinterpret_cast<const f32x4*>(in) + (size_t)i * 2;
    f32x4 a = p[0], b = p[1];
    u16x8 o;
    o[0] = f2bf(a[0]); o[1] = f2bf(a[1]); o[2] = f2bf(a[2]); o[3] = f2bf(a[3]);
    o[4] = f2bf(b[0]); o[5] = f2bf(b[1]); o[6] = f2bf(b[2]); o[7] = f2bf(b[3]);
    reinterpret_cast<u16x8*>(out)[i] = o;
}

// ---------------------------------------------- transpose-cast f32 [R][C] -> bf16 [C][R]
__global__ __launch_bounds__(256) void k_tcast(const float* __restrict__ in,
                                               uint16_t* __restrict__ out, int R, int C) {
    __shared__ uint16_t tile[64][72];
    int t = threadIdx.x;
    int rbase = blockIdx.y * 64, cbase = blockIdx.x * 64;
#pragma unroll
    for (int p = 0; p < 4; ++p) {
        int ir = p * 16 + (t >> 4);
        int ic = (t & 15) * 4;
        f32x4 v = *reinterpret_cast<const f32x4*>(&in[(size_t)(rbase + ir) * C + cbase + ic]);
        tile[ir][ic + 0] = f2bf(v[0]);
        tile[ir][ic + 1] = f2bf(v[1]);
        tile[ir][ic + 2] = f2bf(v[2]);
        tile[ir][ic + 3] = f2bf(v[3]);
    }
    __syncthreads();
#pragma unroll
    for (int p = 0; p < 2; ++p) {
        int oc = p * 32 + (t >> 3);
        int orr = (t & 7) * 8;
        u16x8 o;
#pragma unroll
        for (int e = 0; e < 8; ++e) o[e] = tile[orr + e][oc];
        st8(&out[(size_t)(cbase + oc) * R + rbase + orr], o);
    }
}

// -------------------------------- transpose bf16: in [R][ldin] cols [coff,coff+C) -> out [C][R]
__global__ __launch_bounds__(256) void k_tbf16(const uint16_t* __restrict__ in,
                                               uint16_t* __restrict__ out,
                                               int R, int C, int ldin, int coff) {
    __shared__ uint16_t tile[64][72];
    int t = threadIdx.x;
    int rbase = blockIdx.y * 64, cbase = blockIdx.x * 64;
#pragma unroll
    for (int p = 0; p < 2; ++p) {
        int ir = p * 32 + (t >> 3);
        int ic = (t & 7) * 8;
        u16x8 v = ld8(&in[(size_t)(rbase + ir) * ldin + coff + cbase + ic]);
#pragma unroll
        for (int e = 0; e < 8; ++e) tile[ir][ic + e] = v[e];
    }
    __syncthreads();
#pragma unroll
    for (int p = 0; p < 2; ++p) {
        int oc = p * 32 + (t >> 3);
        int orr = (t & 7) * 8;
        u16x8 o;
#pragma unroll
        for (int e = 0; e < 8; ++e) o[e] = tile[orr + e][oc];
        st8(&out[(size_t)(cbase + oc) * R + rbase + orr], o);
    }
}

// ---------------------------------------------------------------- GEMM C = A @ Bt^T
// A: [M][K] bf16 row-major; Bt: [N][K] bf16 row-major; C: [M][N] bf16 or f32.
// 128x128 tile, BK=32, 4 waves (each a 64x64 quadrant of 4x4 16x16 MFMA tiles).
__global__ __launch_bounds__(256) void k_gemm(const uint16_t* __restrict__ A,
                                              const uint16_t* __restrict__ Bt,
                                              void* __restrict__ Cout,
                                              int M, int N, int K,
                                              int out_bf16, int scale_cols, float qscale) {
    __shared__ __align__(16) uint16_t Asm[128 * 32];
    __shared__ __align__(16) uint16_t Bsm[128 * 32];
    int t = threadIdx.x;
    int w = t >> 6, lane = t & 63, lo = lane & 15, g4 = lane >> 4;
    int mbase = blockIdx.y * 128, nbase = blockIdx.x * 128;
    int moff = (w >> 1) * 64, noff = (w & 1) * 64;
    int srow = t >> 2, scol = (t & 3) * 8;

    f32x4 acc[4][4] = {};

    const uint16_t* pA0 = A + (size_t)(mbase + srow) * K + scol;
    const uint16_t* pA1 = A + (size_t)(mbase + srow + 64) * K + scol;
    const uint16_t* pB0 = Bt + (size_t)(nbase + srow) * K + scol;
    const uint16_t* pB1 = Bt + (size_t)(nbase + srow + 64) * K + scol;

    // swizzled LDS u16 index: (row*32 + col) ^ (((row>>1)&3)<<3)
    int swz = ((srow >> 1) & 3) << 3;  // same for srow and srow+64
    int wi0 = (srow * 32 + scol) ^ swz;
    int wi1 = ((srow + 64) * 32 + scol) ^ swz;

    u16x8 ra0 = ld8(pA0), ra1 = ld8(pA1), rb0 = ld8(pB0), rb1 = ld8(pB1);

    for (int kt = 0; kt < K; kt += 32) {
        st8(&Asm[wi0], ra0); st8(&Asm[wi1], ra1);
        st8(&Bsm[wi0], rb0); st8(&Bsm[wi1], rb1);
        __syncthreads();
        if (kt + 32 < K) {
            pA0 += 32; pA1 += 32; pB0 += 32; pB1 += 32;
            ra0 = ld8(pA0); ra1 = ld8(pA1); rb0 = ld8(pB0); rb1 = ld8(pB1);
        }
        bf16x8 af[4], bfr[4];
#pragma unroll
        for (int i = 0; i < 4; ++i) {
            int ar = moff + i * 16 + lo;
            af[i] = as_bf(ld8(&Asm[(ar * 32 + g4 * 8) ^ (((ar >> 1) & 3) << 3)]));
            int br = noff + i * 16 + lo;
            bfr[i] = as_bf(ld8(&Bsm[(br * 32 + g4 * 8) ^ (((br >> 1) & 3) << 3)]));
        }
#pragma unroll
        for (int i = 0; i < 4; ++i)
#pragma unroll
            for (int j = 0; j < 4; ++j)
                acc[i][j] = __builtin_amdgcn_mfma_f32_16x16x32_bf16(af[i], bfr[j], acc[i][j], 0, 0, 0);
        __syncthreads();
    }

    if (out_bf16) {
        uint16_t* C = (uint16_t*)Cout;
#pragma unroll
        for (int i = 0; i < 4; ++i)
#pragma unroll
            for (int j = 0; j < 4; ++j)
#pragma unroll
                for (int r = 0; r < 4; ++r) {
                    int row = mbase + moff + i * 16 + g4 * 4 + r;
                    int col = nbase + noff + j * 16 + lo;
                    float v = acc[i][j][r];
                    if (col < scale_cols) v *= qscale;
                    C[(size_t)row * N + col] = f2bf(v);
                }
    } else {
        float* C = (float*)Cout;
#pragma unroll
        for (int i = 0; i < 4; ++i)
#pragma unroll
            for (int j = 0; j < 4; ++j)
#pragma unroll
                for (int r = 0; r < 4; ++r) {
                    int row = mbase + moff + i * 16 + g4 * 4 + r;
                    int col = nbase + noff + j * 16 + lo;
                    C[(size_t)row * N + col] = acc[i][j][r];
                }
    }
}

// ---------------------------------------------------------------- causal GQA flash attention
// qkv: [T][3072] bf16 (q pre-scaled by 1/sqrt(hd)); vt: [512][T] bf16 (row = kh*128+d)
// ao:  [T][2048] bf16
__global__ __launch_bounds__(256) void k_attn(const uint16_t* __restrict__ qkv,
                                              const uint16_t* __restrict__ vt,
                                              uint16_t* __restrict__ ao) {
    __shared__ __align__(16) uint16_t Ksm[64 * 128];   // [j][d], swizzled
    __shared__ __align__(16) uint16_t Vsm[128 * 64];   // [d][j], swizzled
    __shared__ __align__(16) uint16_t Psm[4][16 * 64]; // per-wave [i][j], swizzled
    int t = threadIdx.x;
    int w = t >> 6, lane = t & 63, lo = lane & 15, g4 = lane >> 4;
    int qt = (int)gridDim.x - 1 - (int)blockIdx.x;  // longest blocks first
    int h = blockIdx.y;
    int kh = h >> 2;

    // Q fragments (hoisted): row = qt*64 + w*16 + lo, k-slices of 32
    bf16x8 qf[4];
    {
        int qrow = qt * 64 + w * 16 + lo;
        const uint16_t* qp = &qkv[(size_t)qrow * QKVN + h * HD + g4 * 8];
#pragma unroll
        for (int ks = 0; ks < 4; ++ks) qf[ks] = as_bf(ld8(qp + ks * 32));
    }

    f32x4 o[8] = {};
    float mr[4], lr[4];
#pragma unroll
    for (int r = 0; r < 4; ++r) { mr[r] = -INFINITY; lr[r] = 0.f; }

    int krow = t >> 4, kcol = (t & 15) * 8;  // K staging: 16 rows/pass
    int vrow = t >> 3, vcol = (t & 7) * 8;   // V staging: 32 rows/pass

    const uint16_t* kbase = qkv + KCOL + kh * HD;
    const uint16_t* vbase = vt + (size_t)(kh * HD) * T_SEQ;

    u16x8 kreg[4], vreg[4];
    {
        int jb = 0;
#pragma unroll
        for (int p = 0; p < 4; ++p)
            kreg[p] = ld8(&kbase[(size_t)(jb + p * 16 + krow) * QKVN + kcol]);
#pragma unroll
        for (int p = 0; p < 4; ++p)
            vreg[p] = ld8(&vbase[(size_t)(p * 32 + vrow) * T_SEQ + jb + vcol]);
    }

    for (int jt = 0; jt <= qt; ++jt) {
        // write staged tiles (swizzled)
#pragma unroll
        for (int p = 0; p < 4; ++p) {
            int r = p * 16 + krow;
            st8(&Ksm[(r * 128 + kcol) ^ ((r & 7) << 3)], kreg[p]);
        }
#pragma unroll
        for (int p = 0; p < 4; ++p) {
            int d = p * 32 + vrow;
            st8(&Vsm[(d * 64 + vcol) ^ ((d & 7) << 3)], vreg[p]);
        }
        __syncthreads();
        if (jt < qt) {
            int jb = (jt + 1) * 64;
#pragma unroll
            for (int p = 0; p < 4; ++p)
                kreg[p] = ld8(&kbase[(size_t)(jb + p * 16 + krow) * QKVN + kcol]);
#pragma unroll
            for (int p = 0; p < 4; ++p)
                vreg[p] = ld8(&vbase[(size_t)(p * 32 + vrow) * T_SEQ + jb + vcol]);
        }

        // QK^T: s[nt] = 16x16 tile (cols jbase + nt*16 + lo)
        f32x4 s[4] = {};
#pragma unroll
        for (int nt = 0; nt < 4; ++nt) {
            int j = nt * 16 + lo;
#pragma unroll
            for (int ks = 0; ks < 4; ++ks) {
                bf16x8 b = as_bf(ld8(&Ksm[(j * 128 + ks * 32 + g4 * 8) ^ ((j & 7) << 3)]));
                s[nt] = __builtin_amdgcn_mfma_f32_16x16x32_bf16(qf[ks], b, s[nt], 0, 0, 0);
            }
        }

        if (jt == qt) {  // diagonal tile: mask j > i (local coords)
#pragma unroll
            for (int nt = 0; nt < 4; ++nt)
#pragma unroll
                for (int r = 0; r < 4; ++r) {
                    int j = nt * 16 + lo;
                    int i = w * 16 + g4 * 4 + r;
                    if (j > i) s[nt][r] = -INFINITY;
                }
        }

        // online softmax (row r lives at lanes with same g4,r across lo group)
        float pm[4];
#pragma unroll
        for (int r = 0; r < 4; ++r) {
            pm[r] = fmaxf(fmaxf(s[0][r], s[1][r]), fmaxf(s[2][r], s[3][r]));
            pm[r] = fmaxf(pm[r], __shfl_xor(pm[r], 1));
            pm[r] = fmaxf(pm[r], __shfl_xor(pm[r], 2));
            pm[r] = fmaxf(pm[r], __shfl_xor(pm[r], 4));
            pm[r] = fmaxf(pm[r], __shfl_xor(pm[r], 8));
        }
        float al[4];
#pragma unroll
        for (int r = 0; r < 4; ++r) {
            float mn = fmaxf(mr[r], pm[r]);
            al[r] = __expf(mr[r] - mn);
            mr[r] = mn;
        }
        float ps[4] = {0.f, 0.f, 0.f, 0.f};
#pragma unroll
        for (int nt = 0; nt < 4; ++nt)
#pragma unroll
            for (int r = 0; r < 4; ++r) {
                float p = __expf(s[nt][r] - mr[r]);
                s[nt][r] = p;
                ps[r] += p;
            }
        // P -> per-wave LDS (bf16, swizzled)
#pragma unroll
        for (int nt = 0; nt < 4; ++nt)
#pragma unroll
            for (int r = 0; r < 4; ++r) {
                int i = g4 * 4 + r, j = nt * 16 + lo;
                Psm[w][(i * 64 + j) ^ ((i & 7) << 3)] = f2bf(s[nt][r]);
            }
#pragma unroll
        for (int r = 0; r < 4; ++r) {
            ps[r] += __shfl_xor(ps[r], 1);
            ps[r] += __shfl_xor(ps[r], 2);
            ps[r] += __shfl_xor(ps[r], 4);
            ps[r] += __shfl_xor(ps[r], 8);
            lr[r] = lr[r] * al[r] + ps[r];
        }
#pragma unroll
        for (int dt = 0; dt < 8; ++dt)
#pragma unroll
            for (int r = 0; r < 4; ++r) o[dt][r] *= al[r];

        // PV: o[dt] += P(16x64) @ V(64x[dt*16..])
#pragma unroll
        for (int ks2 = 0; ks2 < 2; ++ks2) {
            bf16x8 pa = as_bf(ld8(&Psm[w][(lo * 64 + ks2 * 32 + g4 * 8) ^ ((lo & 7) << 3)]));
#pragma unroll
            for (int dt = 0; dt < 8; ++dt) {
                int d = dt * 16 + lo;
                bf16x8 vb = as_bf(ld8(&Vsm[(d * 64 + ks2 * 32 + g4 * 8) ^ ((d & 7) << 3)]));
                o[dt] = __builtin_amdgcn_mfma_f32_16x16x32_bf16(pa, vb, o[dt], 0, 0, 0);
            }
        }
        __syncthreads();
    }

    // epilogue: ao[i][h*128 + d] = o / l
#pragma unroll
    for (int dt = 0; dt < 8; ++dt)
#pragma unroll
        for (int r = 0; r < 4; ++r) {
            int i = qt * 64 + w * 16 + g4 * 4 + r;
            int col = h * HD + dt * 16 + lo;
            ao[(size_t)i * DMODEL + col] = f2bf(o[dt][r] / lr[r]);
        }
}

// ---------------------------------------------------------------- launch
extern "C" void kernel_launch(void* const* d_in, const int* in_sizes, int n_in,
                              void* d_out, int out_size, void* d_ws, size_t ws_size,
                              hipStream_t stream) {
    (void)in_sizes; (void)n_in; (void)out_size; (void)ws_size;
    const float* x    = (const float*)d_in[0];
    const float* Wqkv = (const float*)d_in[1];
    const float* Wo   = (const float*)d_in[2];
    float* out = (float*)d_out;

    char* ws = (char*)d_ws;
    // byte offsets into workspace (total 50 MB)
    uint16_t* xb   = (uint16_t*)(ws + 0);          //  8 MB  x bf16 [2048][2048]
    uint16_t* wqt  = (uint16_t*)(ws + 8388608);    // 12 MB  Wqkv^T bf16 [3072][2048]
    uint16_t* wot  = (uint16_t*)(ws + 20971520);   //  8 MB  Wo^T bf16 [2048][2048]
    uint16_t* qkvb = (uint16_t*)(ws + 29360128);   // 12 MB  qkv bf16 [2048][3072]
    uint16_t* vtb  = (uint16_t*)(ws + 41943040);   //  2 MB  v^T bf16 [512][2048]
    uint16_t* aob  = (uint16_t*)(ws + 44040192);   //  8 MB  attn out bf16 [2048][2048]

    const float qscale = 0.08838834764831845f;  // 1/sqrt(128)

    k_cast<<<2048, 256, 0, stream>>>(x, xb, 524288);
    k_tcast<<<dim3(48, 32), 256, 0, stream>>>(Wqkv, wqt, 2048, 3072);
    k_tcast<<<dim3(32, 32), 256, 0, stream>>>(Wo, wot, 2048, 2048);
    // qkv = x @ Wqkv (q columns pre-scaled by 1/sqrt(hd))
    k_gemm<<<dim3(24, 16), 256, 0, stream>>>(xb, wqt, qkvb, 2048, 3072, 2048, 1, 2048, qscale);
    // v^T
    k_tbf16<<<dim3(8, 32), 256, 0, stream>>>(qkvb, vtb, 2048, 512, 3072, 2560);
    // attention
    k_attn<<<dim3(32, 16), 256, 0, stream>>>(qkvb, vtb, aob);
    // out = ao @ Wo
    k_gemm<<<dim3(16, 16), 256, 0, stream>>>(aob, wot, out, 2048, 2048, 2048, 0, 0, 1.0f);
}